// Round 7
// baseline (345.604 us; speedup 1.0000x reference)
//
#include <hip/hip_runtime.h>

// SpatialAttention (QKNorm, no 1/sqrt(d)): B=1,T=8,S=1024,HID=1152,H=16,D=72
// Pipeline: cvt x->bf16 | W^T bf16 | fused GEMM->q,k,v^T (BK=64 swizzled global_load_lds,
//           dbuf, 1 barrier/K-step, supertile XCD map) | fused rmsnorm q,k |
//           flash attn (LDS dbuf, swapped QK^T, P in regs) | GEMM -> f32 out

typedef __attribute__((ext_vector_type(4))) short s16x4;
typedef __attribute__((ext_vector_type(8))) short s16x8;
typedef __attribute__((ext_vector_type(4))) float f32x4;

__device__ __forceinline__ unsigned short f2b(float x) {
  unsigned u = __float_as_uint(x);
  u += 0x7FFFu + ((u >> 16) & 1u);
  return (unsigned short)(u >> 16);
}
__device__ __forceinline__ float b2f(unsigned short u) {
  return __uint_as_float(((unsigned)u) << 16);
}
__device__ __forceinline__ void gld16(const void* g, void* l) {
  __builtin_amdgcn_global_load_lds(
      (const __attribute__((address_space(1))) void*)g,
      (__attribute__((address_space(3))) void*)l, 16, 0, 0);
}

// ---------------- x -> bf16 ----------------
__global__ __launch_bounds__(256) void cvt_bf16_kernel(const float* __restrict__ in,
                                                       unsigned short* __restrict__ out,
                                                       int n8) {
  int i = blockIdx.x * 256 + threadIdx.x;
  if (i >= n8) return;
  const float4* p = (const float4*)(in + (size_t)i * 8);
  float4 a = p[0], b = p[1];
  s16x8 r;
  r[0] = (short)f2b(a.x); r[1] = (short)f2b(a.y); r[2] = (short)f2b(a.z); r[3] = (short)f2b(a.w);
  r[4] = (short)f2b(b.x); r[5] = (short)f2b(b.y); r[6] = (short)f2b(b.z); r[7] = (short)f2b(b.w);
  *(s16x8*)(out + (size_t)i * 8) = r;
}

// ---------------- W [K][N] f32 -> WT [N][K] bf16 ----------------
__global__ __launch_bounds__(256) void transpose_cvt_kernel(const float* __restrict__ W,
                                                            unsigned short* __restrict__ WT,
                                                            int K, int N) {
  __shared__ float tile[32][33];
  int n0 = blockIdx.x * 32, k0 = blockIdx.y * 32;
  int tx = threadIdx.x, ty = threadIdx.y;
#pragma unroll
  for (int i = 0; i < 4; i++)
    tile[ty + i * 8][tx] = W[(size_t)(k0 + ty + i * 8) * N + n0 + tx];
  __syncthreads();
#pragma unroll
  for (int i = 0; i < 4; i++)
    WT[(size_t)(n0 + ty + i * 8) * K + k0 + tx] = f2b(tile[tx][ty + i * 8]);
}

// ---------------- GEMM: C[M,N] = A[M,K] @ BT[N,K]^T ----------------
// BK=64, LDS rows 128B (stride = 0 mod 32 banks): 3-bit chunk swizzle
//   LDS(row, slot j) holds global chunk j ^ (row&7)   [linear gld16 dest, pre-swizzled src]
//   fragment read chunk c = ((kk<<2)|(lq>>1)) ^ (l15&7)  -> conflict-free b64 reads.
// No ds_writes at all. Dbuf, ONE barrier/K-step, 8 DMA loads in flight across compute.
// Supertile XCD map (r6, halved FETCH). grid = gx*64, gx%3==0.
// MODE 0: outF f32 row-major (no bias), N=1152.
// MODE 3: fused qkv, N=3456: col<1152 -> qn; <2304 -> kn; else -> vt. bias=[bq;bkv].
template <int MODE>
__global__ __launch_bounds__(256) void gemm_bt_kernel(const unsigned short* __restrict__ A,
                                                      const unsigned short* __restrict__ BT,
                                                      const float* __restrict__ biasq,
                                                      const float* __restrict__ biaskv,
                                                      int N, int gx,
                                                      float* __restrict__ outF,
                                                      unsigned short* __restrict__ qn,
                                                      unsigned short* __restrict__ kn,
                                                      unsigned short* __restrict__ vt) {
  constexpr int K = 1152;
  constexpr int NT = K / 64;  // 18
  __shared__ __align__(16) unsigned short As[2][8192];  // [128 rows][64 k] 16KB each
  __shared__ __align__(16) unsigned short Bs[2][8192];
  int tid = threadIdx.x;
  int lane = tid & 63, wave = tid >> 6;
  int wr = (wave >> 1) * 64, wc = (wave & 1) * 64;
  int l15 = lane & 15, lq = lane >> 4;
  // supertile XCD mapping (bijective: grid = gx*64, gx%3==0)
  int bid = blockIdx.x;
  int xcd = bid & 7;
  int w = bid >> 3;
  int st = w / 24, inner = w - st * 24;
  int ibx = inner % 3, iby = inner / 3;
  int bx = st * 3 + ibx;
  int by = xcd * 8 + iby;
  int brow = by * 128, bcol = bx * 128;
  // staging: thread t handles rows (t>>3)+32i, slot j = t&7; source chunk = j ^ (row&7).
  // LDS dest is wave-uniform base + lane*16B (rows 8w..8w+7 per (wave,i)) -> linear.
  int srow0 = tid >> 3, sj = tid & 7;
  const unsigned short* Asrc[4];
  const unsigned short* Bsrc[4];
#pragma unroll
  for (int i = 0; i < 4; i++) {
    int row = srow0 + 32 * i;
    int ch = sj ^ (row & 7);
    Asrc[i] = A + (size_t)(brow + row) * K + ch * 8;
    Bsrc[i] = BT + (size_t)(bcol + row) * K + ch * 8;
  }
#define STAGE(KT, BUF)                                                   \
  {                                                                      \
    int kb = (KT) * 64;                                                  \
    _Pragma("unroll") for (int i = 0; i < 4; i++) {                      \
      gld16(Asrc[i] + kb, &As[BUF][(wave * 8 + 32 * i) * 64]);           \
      gld16(Bsrc[i] + kb, &Bs[BUF][(wave * 8 + 32 * i) * 64]);           \
    }                                                                    \
  }
  // fragment-read swizzle constants
  int rsw = l15 & 7;
  int sub4 = (lq & 1) << 2;           // u16 offset within 16B chunk (8B half)
  int cA = (lq >> 1) ^ rsw;           // chunk for kk=0 lo; kk-> ^ (kk<<2); hi -> ^2
  STAGE(0, 0);
  f32x4 acc[4][4] = {};
  for (int kt = 0; kt < NT; kt++) {
    __syncthreads();  // compiler drains vmcnt(0): buf[cur]'s DMA (issued last iter) done
    int cur = kt & 1;
    if (kt + 1 < NT) STAGE(kt + 1, cur ^ 1);
#pragma unroll
    for (int kk = 0; kk < 2; kk++) {
      int cLo = (cA ^ (kk << 2)) * 8;
      int cHi = ((cA ^ (kk << 2)) ^ 2) * 8;
      s16x8 af[4], bf[4];
#pragma unroll
      for (int m = 0; m < 4; m++) {
        int ra = (wr + m * 16 + l15) * 64 + sub4;
        s16x4 lo = *(const s16x4*)&As[cur][ra + cLo];
        s16x4 hi = *(const s16x4*)&As[cur][ra + cHi];
        af[m] = __builtin_shufflevector(lo, hi, 0, 1, 2, 3, 4, 5, 6, 7);
        int rb = (wc + m * 16 + l15) * 64 + sub4;
        s16x4 blo = *(const s16x4*)&Bs[cur][rb + cLo];
        s16x4 bhi = *(const s16x4*)&Bs[cur][rb + cHi];
        bf[m] = __builtin_shufflevector(blo, bhi, 0, 1, 2, 3, 4, 5, 6, 7);
      }
      __builtin_amdgcn_s_setprio(1);
#pragma unroll
      for (int m = 0; m < 4; m++)
#pragma unroll
        for (int n = 0; n < 4; n++)
          acc[m][n] = __builtin_amdgcn_mfma_f32_16x16x32_bf16(af[m], bf[n], acc[m][n], 0, 0, 0);
      __builtin_amdgcn_s_setprio(0);
    }
  }
#undef STAGE
#pragma unroll
  for (int m = 0; m < 4; m++) {
#pragma unroll
    for (int n = 0; n < 4; n++) {
#pragma unroll
      for (int r = 0; r < 4; r++) {
        int grow = brow + wr + m * 16 + lq * 4 + r;
        int gcol = bcol + wc + n * 16 + l15;
        float v = acc[m][n][r];
        if (MODE == 0) {
          outF[(size_t)grow * N + gcol] = v;
        } else {
          v += (gcol < 1152) ? biasq[gcol] : biaskv[gcol - 1152];
          int t = grow >> 10, s = grow & 1023;
          if (gcol < 2304) {
            int c = (gcol < 1152) ? gcol : gcol - 1152;
            int h = c / 72, d = c - h * 72;
            unsigned short* dst = (gcol < 1152) ? qn : kn;
            dst[((size_t)((t * 16 + h) * 1024 + s)) * 96 + d] = f2b(v);
          } else {
            int c = gcol - 2304;
            int h = c / 72, d = c - h * 72;
            vt[((size_t)((t * 16 + h) * 80 + d)) * 1024 + s] = f2b(v);
          }
        }
      }
    }
  }
}

// ---------------- fused per-(row,head) RMSNorm for q and k, zero-fills pads ----------------
__global__ __launch_bounds__(256) void rmsnorm2_kernel(unsigned short* __restrict__ qn,
                                                       unsigned short* __restrict__ kn,
                                                       const float* __restrict__ qg,
                                                       const float* __restrict__ kg) {
  int r = blockIdx.x * 4 + (threadIdx.x >> 6);  // 0..262143
  int isK = r >= 131072;
  int g = isK ? r - 131072 : r;                 // g = th*1024 + s
  unsigned short* buf = isK ? kn : qn;
  const float* gamma = isK ? kg : qg;
  int h = (g >> 10) & 15;
  size_t base = (size_t)g * 96;
  int l = threadIdx.x & 63;
  float e0 = b2f(buf[base + l]);
  float e1 = 0.f;
  if (l < 8) e1 = b2f(buf[base + 64 + l]);
  float ss = e0 * e0 + e1 * e1;
#pragma unroll
  for (int m = 1; m < 64; m <<= 1) ss += __shfl_xor(ss, m);
  float sc = rsqrtf(ss * (1.0f / 72.0f) + 1e-6f);
  buf[base + l] = f2b(e0 * sc * gamma[h * 72 + l]);
  if (l < 32) {
    float v = 0.f;
    if (l < 8) v = e1 * sc * gamma[h * 72 + 64 + l];
    buf[base + 64 + l] = f2b(v);
  }
}

// ---------------- flash attention: LDS dbuf 2-phase, swapped QK^T, P in registers ----------------
// Qn,Kn: [th][1024][96] bf16 (pads zeroed). VtG: [th][80][1024] bf16 (rows 72..79 garbage,
// pollutes only unstored d>=72 outputs). att: [8192][1152] bf16.
__global__ __launch_bounds__(256) void attn_kernel(const unsigned short* __restrict__ Qn,
                                                   const unsigned short* __restrict__ Kn,
                                                   const unsigned short* __restrict__ VtG,
                                                   unsigned short* __restrict__ att) {
  __shared__ unsigned short Kl[2][64][100];  // pad 100: conflict-light fragment reads
  __shared__ unsigned short Vt[2][80][76];   // pad 76
  int tid = threadIdx.x;
  int lane = tid & 63, wave = tid >> 6;
  int l15 = lane & 15, lq = lane >> 4, kf = lq * 4;
  // bijective XCD swizzle: nwg=2048
  int bid = blockIdx.x;
  int orig = (bid & 7) * 256 + (bid >> 3);
  int qb = orig & 15, th = orig >> 4;
  int t = th >> 4, h = th & 15;
  const unsigned short* Q = Qn + (size_t)th * 1024 * 96;
  const unsigned short* Kp = Kn + (size_t)th * 1024 * 96;
  const unsigned short* Vg = VtG + (size_t)th * 80 * 1024;
  int qrow0 = qb * 64 + wave * 16;
  // staging chunk geometry (per thread: 3 K chunks + up to 3 V chunks)
  int krow[3], kco[3], vd[3], vco[3];
#pragma unroll
  for (int i = 0; i < 3; i++) {
    int c = tid + i * 256;           // 0..767: K chunks (64 rows x 12 chunks)
    krow[i] = c / 12;
    kco[i] = c - 12 * krow[i];
    int cc = tid + i * 256;          // 0..639: V chunks (80 rows x 8 chunks)
    vd[i] = cc >> 3;
    vco[i] = cc & 7;
  }
  bool v2 = tid < 128;               // third V chunk valid only for cc<640
  s16x8 sk[3], sv[3];
  // Q fragments (B-operand: col=l15=q, k=d)
  s16x8 qf[3];
#pragma unroll
  for (int c = 0; c < 3; c++) {
    const unsigned short* p = Q + (size_t)(qrow0 + l15) * 96 + c * 32 + kf;
    s16x4 lo = *(const s16x4*)p;
    s16x4 hi = *(const s16x4*)(p + 16);
    qf[c] = __builtin_shufflevector(lo, hi, 0, 1, 2, 3, 4, 5, 6, 7);
  }
  f32x4 o[5] = {};                   // O[q=4lq+r][d=l15+16v]
  float m_r = -3.0e38f, l_r = 0.f;   // per-lane state for q = l15

  // prologue: stage tile 0 into buf 0
#pragma unroll
  for (int i = 0; i < 3; i++)
    sk[i] = *(const s16x8*)(Kp + (size_t)krow[i] * 96 + kco[i] * 8);
#pragma unroll
  for (int i = 0; i < 2; i++)
    sv[i] = *(const s16x8*)(Vg + (size_t)vd[i] * 1024 + vco[i] * 8);
  if (v2) sv[2] = *(const s16x8*)(Vg + (size_t)vd[2] * 1024 + vco[2] * 8);
#pragma unroll
  for (int i = 0; i < 3; i++) *(s16x8*)&Kl[0][krow[i]][kco[i] * 8] = sk[i];
#pragma unroll
  for (int i = 0; i < 2; i++) *(s16x8*)&Vt[0][vd[i]][vco[i] * 8] = sv[i];
  if (v2) *(s16x8*)&Vt[0][vd[2]][vco[2] * 8] = sv[2];

  for (int tt = 0; tt < 16; tt++) {
    __syncthreads();
    int cur = tt & 1;
    if (tt < 15) {
      int kv1 = (tt + 1) * 64;
#pragma unroll
      for (int i = 0; i < 3; i++)
        sk[i] = *(const s16x8*)(Kp + (size_t)(kv1 + krow[i]) * 96 + kco[i] * 8);
#pragma unroll
      for (int i = 0; i < 2; i++)
        sv[i] = *(const s16x8*)(Vg + (size_t)vd[i] * 1024 + kv1 + vco[i] * 8);
      if (v2) sv[2] = *(const s16x8*)(Vg + (size_t)vd[2] * 1024 + kv1 + vco[2] * 8);
    }
    // S^T = mfma(K, Q): st[n][r] = S[q=l15][kv = n*16 + 4*lq + r]
    f32x4 st[4];
    __builtin_amdgcn_s_setprio(1);
#pragma unroll
    for (int n = 0; n < 4; n++) {
      f32x4 a = {};
#pragma unroll
      for (int c = 0; c < 3; c++) {
        s16x4 lo = *(const s16x4*)&Kl[cur][n * 16 + l15][c * 32 + kf];
        s16x4 hi = *(const s16x4*)&Kl[cur][n * 16 + l15][c * 32 + kf + 16];
        s16x8 kfr = __builtin_shufflevector(lo, hi, 0, 1, 2, 3, 4, 5, 6, 7);
        a = __builtin_amdgcn_mfma_f32_16x16x32_bf16(kfr, qf[c], a, 0, 0, 0);
      }
      st[n] = a;
    }
    __builtin_amdgcn_s_setprio(0);
    // online softmax for q = l15 (16 local + lq-group shfl reduce)
    float tmax = st[0][0];
#pragma unroll
    for (int n = 0; n < 4; n++)
#pragma unroll
      for (int r = 0; r < 4; r++) tmax = fmaxf(tmax, st[n][r]);
    tmax = fmaxf(tmax, __shfl_xor(tmax, 16));
    tmax = fmaxf(tmax, __shfl_xor(tmax, 32));
    float mn = fmaxf(m_r, tmax);
    float scale = __expf(m_r - mn);
    m_r = mn;
    float sum = 0.f;
#pragma unroll
    for (int n = 0; n < 4; n++)
#pragma unroll
      for (int r = 0; r < 4; r++) {
        float p = __expf(st[n][r] - mn);
        st[n][r] = p;
        sum += p;
      }
    sum += __shfl_xor(sum, 16);
    sum += __shfl_xor(sum, 32);
    l_r = l_r * scale + sum;
    // rescale O (scale for q=4lq+r lives at lane 4lq+r)
#pragma unroll
    for (int r = 0; r < 4; r++) {
      float scq = __shfl(scale, 4 * lq + r);
#pragma unroll
      for (int v = 0; v < 5; v++) o[v][r] *= scq;
    }
    // P fragments directly from st registers (A-operand: row=l15=q, k=kv)
    __builtin_amdgcn_s_setprio(1);
#pragma unroll
    for (int b = 0; b < 2; b++) {
      s16x8 pf;
#pragma unroll
      for (int j = 0; j < 8; j++) pf[j] = (short)f2b(st[2 * b + (j >> 2)][j & 3]);
#pragma unroll
      for (int v = 0; v < 5; v++) {
        s16x4 vlo = *(const s16x4*)&Vt[cur][v * 16 + l15][b * 32 + kf];
        s16x4 vhi = *(const s16x4*)&Vt[cur][v * 16 + l15][b * 32 + kf + 16];
        s16x8 vf = __builtin_shufflevector(vlo, vhi, 0, 1, 2, 3, 4, 5, 6, 7);
        o[v] = __builtin_amdgcn_mfma_f32_16x16x32_bf16(pf, vf, o[v], 0, 0, 0);
      }
    }
    __builtin_amdgcn_s_setprio(0);
    // write-late: next tile into the other buffer
    if (tt < 15) {
      int nxt = cur ^ 1;
#pragma unroll
      for (int i = 0; i < 3; i++) *(s16x8*)&Kl[nxt][krow[i]][kco[i] * 8] = sk[i];
#pragma unroll
      for (int i = 0; i < 2; i++) *(s16x8*)&Vt[nxt][vd[i]][vco[i] * 8] = sv[i];
      if (v2) *(s16x8*)&Vt[nxt][vd[2]][vco[2] * 8] = sv[2];
    }
  }
  // epilogue: normalize by l (lives at lane 4lq+r), store d<72
#pragma unroll
  for (int r = 0; r < 4; r++) {
    float inv = 1.0f / __shfl(l_r, 4 * lq + r);
    int qrow = qrow0 + 4 * lq + r;
    size_t rowbase = (size_t)(t * 1024 + qrow) * 1152 + h * 72;
#pragma unroll
    for (int v = 0; v < 5; v++) {
      int d = v * 16 + l15;
      if (d < 72) att[rowbase + d] = f2b(o[v][r] * inv);
    }
  }
}

extern "C" void kernel_launch(void* const* d_in, const int* in_sizes, int n_in,
                              void* d_out, int out_size, void* d_ws, size_t ws_size,
                              hipStream_t stream) {
  const float* x   = (const float*)d_in[0];
  const float* Wq  = (const float*)d_in[1];
  const float* bq  = (const float*)d_in[2];
  const float* Wkv = (const float*)d_in[3];
  const float* bkv = (const float*)d_in[4];
  const float* qg  = (const float*)d_in[5];
  const float* kg  = (const float*)d_in[6];
  const float* Wo  = (const float*)d_in[7];
  float* out = (float*)d_out;

  char* w = (char*)d_ws;
  unsigned short* xb   = (unsigned short*)w; w += (size_t)8192 * 1152 * 2;     // 18.9 MB
  unsigned short* WqT  = (unsigned short*)w; w += (size_t)1152 * 1152 * 2;     // contiguous with WkvT -> [3456][1152]
  unsigned short* WkvT = (unsigned short*)w; w += (size_t)2304 * 1152 * 2;
  unsigned short* WoT  = (unsigned short*)w; w += (size_t)1152 * 1152 * 2;
  unsigned short* qn   = (unsigned short*)w; w += (size_t)128 * 1024 * 96 * 2; // 25.2 MB
  unsigned short* kn   = (unsigned short*)w; w += (size_t)128 * 1024 * 96 * 2; // 25.2 MB
  unsigned short* vt   = (unsigned short*)w; w += (size_t)128 * 80 * 1024 * 2; // 21.0 MB
  unsigned short* att  = (unsigned short*)w; w += (size_t)8192 * 1152 * 2;     // 18.9 MB

  cvt_bf16_kernel<<<4608, 256, 0, stream>>>(x, xb, 9437184 / 8);
  transpose_cvt_kernel<<<dim3(36, 36), dim3(32, 8), 0, stream>>>(Wq, WqT, 1152, 1152);
  transpose_cvt_kernel<<<dim3(72, 36), dim3(32, 8), 0, stream>>>(Wkv, WkvT, 1152, 2304);
  transpose_cvt_kernel<<<dim3(36, 36), dim3(32, 8), 0, stream>>>(Wo, WoT, 1152, 1152);

  // fused q,k,v^T GEMM: BT = [WqT ; WkvT] = [3456][1152], grid 27*64=1728
  gemm_bt_kernel<3><<<1728, 256, 0, stream>>>(xb, WqT, bq, bkv, 3456, 27, nullptr, qn, kn, vt);
  rmsnorm2_kernel<<<65536, 256, 0, stream>>>(qn, kn, qg, kg);

  attn_kernel<<<2048, 256, 0, stream>>>(qn, kn, vt, att);

  // out = att @ WoT^T, grid 9*64=576
  gemm_bt_kernel<0><<<576, 256, 0, stream>>>(att, WoT, nullptr, nullptr, 1152, 9, out, nullptr, nullptr, nullptr);
}

// Round 8
// 327.791 us; speedup vs baseline: 1.0543x; 1.0543x over previous
//
#include <hip/hip_runtime.h>

// SpatialAttention (QKNorm, no 1/sqrt(d)): B=1,T=8,S=1024,HID=1152,H=16,D=72
// Pipeline: cvt x->bf16 | W^T bf16 | fused GEMM->q,k,v^T (BK=32 gld16, TRIPLE buffer,
//           counted vmcnt(4) + raw s_barrier, supertile XCD map) | fused rmsnorm q,k |
//           flash attn (LDS dbuf, swapped QK^T, P in regs) | GEMM -> f32 out

typedef __attribute__((ext_vector_type(4))) short s16x4;
typedef __attribute__((ext_vector_type(8))) short s16x8;
typedef __attribute__((ext_vector_type(4))) float f32x4;

__device__ __forceinline__ unsigned short f2b(float x) {
  unsigned u = __float_as_uint(x);
  u += 0x7FFFu + ((u >> 16) & 1u);
  return (unsigned short)(u >> 16);
}
__device__ __forceinline__ float b2f(unsigned short u) {
  return __uint_as_float(((unsigned)u) << 16);
}
__device__ __forceinline__ void gld16(const void* g, void* l) {
  __builtin_amdgcn_global_load_lds(
      (const __attribute__((address_space(1))) void*)g,
      (__attribute__((address_space(3))) void*)l, 16, 0, 0);
}

// ---------------- x -> bf16 ----------------
__global__ __launch_bounds__(256) void cvt_bf16_kernel(const float* __restrict__ in,
                                                       unsigned short* __restrict__ out,
                                                       int n8) {
  int i = blockIdx.x * 256 + threadIdx.x;
  if (i >= n8) return;
  const float4* p = (const float4*)(in + (size_t)i * 8);
  float4 a = p[0], b = p[1];
  s16x8 r;
  r[0] = (short)f2b(a.x); r[1] = (short)f2b(a.y); r[2] = (short)f2b(a.z); r[3] = (short)f2b(a.w);
  r[4] = (short)f2b(b.x); r[5] = (short)f2b(b.y); r[6] = (short)f2b(b.z); r[7] = (short)f2b(b.w);
  *(s16x8*)(out + (size_t)i * 8) = r;
}

// ---------------- W [K][N] f32 -> WT [N][K] bf16 ----------------
__global__ __launch_bounds__(256) void transpose_cvt_kernel(const float* __restrict__ W,
                                                            unsigned short* __restrict__ WT,
                                                            int K, int N) {
  __shared__ float tile[32][33];
  int n0 = blockIdx.x * 32, k0 = blockIdx.y * 32;
  int tx = threadIdx.x, ty = threadIdx.y;
#pragma unroll
  for (int i = 0; i < 4; i++)
    tile[ty + i * 8][tx] = W[(size_t)(k0 + ty + i * 8) * N + n0 + tx];
  __syncthreads();
#pragma unroll
  for (int i = 0; i < 4; i++)
    WT[(size_t)(n0 + ty + i * 8) * K + k0 + tx] = f2b(tile[tx][ty + i * 8]);
}

// ---------------- GEMM: C[M,N] = A[M,K] @ BT[N,K]^T ----------------
// BK=32, triple-buffered gld16 (8 KB/tile/operand), counted vmcnt:
//   per step: [vmcnt(4); s_barrier]  -> tile kt landed, tile kt+1's 4 loads STAY in flight
//             STAGE(kt+2 -> buf[(kt+2)%3])  (WAR-safe: readers finished pre-barrier)
//             compute buf[kt%3]
// Chunk swizzle: LDS slot j of row r holds global chunk j ^ f(r), f = bits{1,3} of r;
// read slot = (lq>>1 | hi*2) ^ f -> 4 lanes/bank-slot (the b64 floor). No ds_writes.
// Supertile XCD map. grid = gx*64, gx%3==0.
// MODE 0: outF f32 row-major (no bias), N=1152.
// MODE 3: fused qkv, N=3456: col<1152 -> qn; <2304 -> kn; else -> vt. bias=[bq;bkv].
template <int MODE>
__global__ __launch_bounds__(256) void gemm_bt_kernel(const unsigned short* __restrict__ A,
                                                      const unsigned short* __restrict__ BT,
                                                      const float* __restrict__ biasq,
                                                      const float* __restrict__ biaskv,
                                                      int N, int gx,
                                                      float* __restrict__ outF,
                                                      unsigned short* __restrict__ qn,
                                                      unsigned short* __restrict__ kn,
                                                      unsigned short* __restrict__ vt) {
  constexpr int K = 1152;
  constexpr int NT = K / 32;  // 36
  __shared__ __align__(16) unsigned short As[3 * 4096];  // 3 bufs x [128 rows][32 k]
  __shared__ __align__(16) unsigned short Bs[3 * 4096];
  int tid = threadIdx.x;
  int lane = tid & 63, wave = tid >> 6;
  int wr = (wave >> 1) * 64, wc = (wave & 1) * 64;
  int l15 = lane & 15, lq = lane >> 4;
  // supertile XCD mapping (bijective: grid = gx*64, gx%3==0)
  int bid = blockIdx.x;
  int xcd = bid & 7;
  int w = bid >> 3;
  int st = w / 24, inner = w - st * 24;
  int ibx = inner % 3, iby = inner / 3;
  int bx = st * 3 + ibx;
  int by = xcd * 8 + iby;
  int brow = by * 128, bcol = bx * 128;
  // staging: chunk c = tid + 256*i (i=0,1): row = c>>2, slot j = c&3,
  // source chunk = j ^ f(row), f(row) = ((row>>1)&1)<<1 | ((row>>3)&1).
  // LDS dest linear at 16B*c -> wave-uniform base + lane*16.
  const unsigned short* AsrcP[2];
  const unsigned short* BsrcP[2];
  int dst0[2];
#pragma unroll
  for (int i = 0; i < 2; i++) {
    int c = tid + 256 * i;
    int row = c >> 2, j = c & 3;
    int f = (((row >> 1) & 1) << 1) | ((row >> 3) & 1);
    int ch = j ^ f;
    AsrcP[i] = A + (size_t)(brow + row) * K + ch * 8;
    BsrcP[i] = BT + (size_t)(bcol + row) * K + ch * 8;
    dst0[i] = (wave * 64 + 256 * i) * 8;  // u16 offset of wave's chunk block
  }
#define STAGE(KT, BUF)                                          \
  {                                                             \
    int kb = (KT) * 32;                                         \
    gld16(AsrcP[0] + kb, &As[(BUF) * 4096 + dst0[0]]);          \
    gld16(BsrcP[0] + kb, &Bs[(BUF) * 4096 + dst0[0]]);          \
    gld16(AsrcP[1] + kb, &As[(BUF) * 4096 + dst0[1]]);          \
    gld16(BsrcP[1] + kb, &Bs[(BUF) * 4096 + dst0[1]]);          \
  }
  // fragment-read offsets: row r (r&15 = l15): f = ((l15>>1)&1)<<1 | ((l15>>3)&1)
  int fr = (((l15 >> 1) & 1) << 1) | ((l15 >> 3) & 1);
  int loff = ((lq >> 1) ^ fr) * 8 + (lq & 1) * 4;  // k = 4lq..4lq+3
  int hoff = loff ^ 16;                            // k = 16+4lq.. (slot^2)
  // prologue: tiles 0,1 -> bufs 0,1 (8 loads in flight)
  STAGE(0, 0);
  STAGE(1, 1);
  f32x4 acc[4][4] = {};
  int cur = 0;
  for (int kt = 0; kt < NT; kt++) {
    if (kt < NT - 1)
      asm volatile("s_waitcnt vmcnt(4)\n\ts_barrier" ::: "memory");
    else
      asm volatile("s_waitcnt vmcnt(0)\n\ts_barrier" ::: "memory");
    if (kt + 2 < NT) {
      int nb = (cur == 0) ? 2 : cur - 1;  // (kt+2)%3
      STAGE(kt + 2, nb);
    }
    int ab = cur * 4096;
    s16x8 af[4], bf[4];
#pragma unroll
    for (int m = 0; m < 4; m++) {
      int ra = ab + (wr + m * 16 + l15) * 32;
      s16x4 lo = *(const s16x4*)&As[ra + loff];
      s16x4 hi = *(const s16x4*)&As[ra + hoff];
      af[m] = __builtin_shufflevector(lo, hi, 0, 1, 2, 3, 4, 5, 6, 7);
      int rb = ab + (wc + m * 16 + l15) * 32;
      s16x4 blo = *(const s16x4*)&Bs[rb + loff];
      s16x4 bhi = *(const s16x4*)&Bs[rb + hoff];
      bf[m] = __builtin_shufflevector(blo, bhi, 0, 1, 2, 3, 4, 5, 6, 7);
    }
    __builtin_amdgcn_s_setprio(1);
#pragma unroll
    for (int m = 0; m < 4; m++)
#pragma unroll
      for (int n = 0; n < 4; n++)
        acc[m][n] = __builtin_amdgcn_mfma_f32_16x16x32_bf16(af[m], bf[n], acc[m][n], 0, 0, 0);
    __builtin_amdgcn_s_setprio(0);
    cur = (cur == 2) ? 0 : cur + 1;
  }
#undef STAGE
#pragma unroll
  for (int m = 0; m < 4; m++) {
#pragma unroll
    for (int n = 0; n < 4; n++) {
#pragma unroll
      for (int r = 0; r < 4; r++) {
        int grow = brow + wr + m * 16 + lq * 4 + r;
        int gcol = bcol + wc + n * 16 + l15;
        float v = acc[m][n][r];
        if (MODE == 0) {
          outF[(size_t)grow * N + gcol] = v;
        } else {
          v += (gcol < 1152) ? biasq[gcol] : biaskv[gcol - 1152];
          int t = grow >> 10, s = grow & 1023;
          if (gcol < 2304) {
            int c = (gcol < 1152) ? gcol : gcol - 1152;
            int h = c / 72, d = c - h * 72;
            unsigned short* dst = (gcol < 1152) ? qn : kn;
            dst[((size_t)((t * 16 + h) * 1024 + s)) * 96 + d] = f2b(v);
          } else {
            int c = gcol - 2304;
            int h = c / 72, d = c - h * 72;
            vt[((size_t)((t * 16 + h) * 80 + d)) * 1024 + s] = f2b(v);
          }
        }
      }
    }
  }
}

// ---------------- fused per-(row,head) RMSNorm for q and k, zero-fills pads ----------------
__global__ __launch_bounds__(256) void rmsnorm2_kernel(unsigned short* __restrict__ qn,
                                                       unsigned short* __restrict__ kn,
                                                       const float* __restrict__ qg,
                                                       const float* __restrict__ kg) {
  int r = blockIdx.x * 4 + (threadIdx.x >> 6);  // 0..262143
  int isK = r >= 131072;
  int g = isK ? r - 131072 : r;                 // g = th*1024 + s
  unsigned short* buf = isK ? kn : qn;
  const float* gamma = isK ? kg : qg;
  int h = (g >> 10) & 15;
  size_t base = (size_t)g * 96;
  int l = threadIdx.x & 63;
  float e0 = b2f(buf[base + l]);
  float e1 = 0.f;
  if (l < 8) e1 = b2f(buf[base + 64 + l]);
  float ss = e0 * e0 + e1 * e1;
#pragma unroll
  for (int m = 1; m < 64; m <<= 1) ss += __shfl_xor(ss, m);
  float sc = rsqrtf(ss * (1.0f / 72.0f) + 1e-6f);
  buf[base + l] = f2b(e0 * sc * gamma[h * 72 + l]);
  if (l < 32) {
    float v = 0.f;
    if (l < 8) v = e1 * sc * gamma[h * 72 + 64 + l];
    buf[base + 64 + l] = f2b(v);
  }
}

// ---------------- flash attention: LDS dbuf 2-phase, swapped QK^T, P in registers ----------------
// Qn,Kn: [th][1024][96] bf16 (pads zeroed). VtG: [th][80][1024] bf16 (rows 72..79 garbage,
// pollutes only unstored d>=72 outputs). att: [8192][1152] bf16.
__global__ __launch_bounds__(256) void attn_kernel(const unsigned short* __restrict__ Qn,
                                                   const unsigned short* __restrict__ Kn,
                                                   const unsigned short* __restrict__ VtG,
                                                   unsigned short* __restrict__ att) {
  __shared__ unsigned short Kl[2][64][100];  // pad 100: conflict-light fragment reads
  __shared__ unsigned short Vt[2][80][76];   // pad 76
  int tid = threadIdx.x;
  int lane = tid & 63, wave = tid >> 6;
  int l15 = lane & 15, lq = lane >> 4, kf = lq * 4;
  // bijective XCD swizzle: nwg=2048
  int bid = blockIdx.x;
  int orig = (bid & 7) * 256 + (bid >> 3);
  int qb = orig & 15, th = orig >> 4;
  int t = th >> 4, h = th & 15;
  const unsigned short* Q = Qn + (size_t)th * 1024 * 96;
  const unsigned short* Kp = Kn + (size_t)th * 1024 * 96;
  const unsigned short* Vg = VtG + (size_t)th * 80 * 1024;
  int qrow0 = qb * 64 + wave * 16;
  // staging chunk geometry (per thread: 3 K chunks + up to 3 V chunks)
  int krow[3], kco[3], vd[3], vco[3];
#pragma unroll
  for (int i = 0; i < 3; i++) {
    int c = tid + i * 256;           // 0..767: K chunks (64 rows x 12 chunks)
    krow[i] = c / 12;
    kco[i] = c - 12 * krow[i];
    int cc = tid + i * 256;          // 0..639: V chunks (80 rows x 8 chunks)
    vd[i] = cc >> 3;
    vco[i] = cc & 7;
  }
  bool v2 = tid < 128;               // third V chunk valid only for cc<640
  s16x8 sk[3], sv[3];
  // Q fragments (B-operand: col=l15=q, k=d)
  s16x8 qf[3];
#pragma unroll
  for (int c = 0; c < 3; c++) {
    const unsigned short* p = Q + (size_t)(qrow0 + l15) * 96 + c * 32 + kf;
    s16x4 lo = *(const s16x4*)p;
    s16x4 hi = *(const s16x4*)(p + 16);
    qf[c] = __builtin_shufflevector(lo, hi, 0, 1, 2, 3, 4, 5, 6, 7);
  }
  f32x4 o[5] = {};                   // O[q=4lq+r][d=l15+16v]
  float m_r = -3.0e38f, l_r = 0.f;   // per-lane state for q = l15

  // prologue: stage tile 0 into buf 0
#pragma unroll
  for (int i = 0; i < 3; i++)
    sk[i] = *(const s16x8*)(Kp + (size_t)krow[i] * 96 + kco[i] * 8);
#pragma unroll
  for (int i = 0; i < 2; i++)
    sv[i] = *(const s16x8*)(Vg + (size_t)vd[i] * 1024 + vco[i] * 8);
  if (v2) sv[2] = *(const s16x8*)(Vg + (size_t)vd[2] * 1024 + vco[2] * 8);
#pragma unroll
  for (int i = 0; i < 3; i++) *(s16x8*)&Kl[0][krow[i]][kco[i] * 8] = sk[i];
#pragma unroll
  for (int i = 0; i < 2; i++) *(s16x8*)&Vt[0][vd[i]][vco[i] * 8] = sv[i];
  if (v2) *(s16x8*)&Vt[0][vd[2]][vco[2] * 8] = sv[2];

  for (int tt = 0; tt < 16; tt++) {
    __syncthreads();
    int cur = tt & 1;
    if (tt < 15) {
      int kv1 = (tt + 1) * 64;
#pragma unroll
      for (int i = 0; i < 3; i++)
        sk[i] = *(const s16x8*)(Kp + (size_t)(kv1 + krow[i]) * 96 + kco[i] * 8);
#pragma unroll
      for (int i = 0; i < 2; i++)
        sv[i] = *(const s16x8*)(Vg + (size_t)vd[i] * 1024 + kv1 + vco[i] * 8);
      if (v2) sv[2] = *(const s16x8*)(Vg + (size_t)vd[2] * 1024 + kv1 + vco[2] * 8);
    }
    // S^T = mfma(K, Q): st[n][r] = S[q=l15][kv = n*16 + 4*lq + r]
    f32x4 st[4];
    __builtin_amdgcn_s_setprio(1);
#pragma unroll
    for (int n = 0; n < 4; n++) {
      f32x4 a = {};
#pragma unroll
      for (int c = 0; c < 3; c++) {
        s16x4 lo = *(const s16x4*)&Kl[cur][n * 16 + l15][c * 32 + kf];
        s16x4 hi = *(const s16x4*)&Kl[cur][n * 16 + l15][c * 32 + kf + 16];
        s16x8 kfr = __builtin_shufflevector(lo, hi, 0, 1, 2, 3, 4, 5, 6, 7);
        a = __builtin_amdgcn_mfma_f32_16x16x32_bf16(kfr, qf[c], a, 0, 0, 0);
      }
      st[n] = a;
    }
    __builtin_amdgcn_s_setprio(0);
    // online softmax for q = l15 (16 local + lq-group shfl reduce)
    float tmax = st[0][0];
#pragma unroll
    for (int n = 0; n < 4; n++)
#pragma unroll
      for (int r = 0; r < 4; r++) tmax = fmaxf(tmax, st[n][r]);
    tmax = fmaxf(tmax, __shfl_xor(tmax, 16));
    tmax = fmaxf(tmax, __shfl_xor(tmax, 32));
    float mn = fmaxf(m_r, tmax);
    float scale = __expf(m_r - mn);
    m_r = mn;
    float sum = 0.f;
#pragma unroll
    for (int n = 0; n < 4; n++)
#pragma unroll
      for (int r = 0; r < 4; r++) {
        float p = __expf(st[n][r] - mn);
        st[n][r] = p;
        sum += p;
      }
    sum += __shfl_xor(sum, 16);
    sum += __shfl_xor(sum, 32);
    l_r = l_r * scale + sum;
    // rescale O (scale for q=4lq+r lives at lane 4lq+r)
#pragma unroll
    for (int r = 0; r < 4; r++) {
      float scq = __shfl(scale, 4 * lq + r);
#pragma unroll
      for (int v = 0; v < 5; v++) o[v][r] *= scq;
    }
    // P fragments directly from st registers (A-operand: row=l15=q, k=kv)
    __builtin_amdgcn_s_setprio(1);
#pragma unroll
    for (int b = 0; b < 2; b++) {
      s16x8 pf;
#pragma unroll
      for (int j = 0; j < 8; j++) pf[j] = (short)f2b(st[2 * b + (j >> 2)][j & 3]);
#pragma unroll
      for (int v = 0; v < 5; v++) {
        s16x4 vlo = *(const s16x4*)&Vt[cur][v * 16 + l15][b * 32 + kf];
        s16x4 vhi = *(const s16x4*)&Vt[cur][v * 16 + l15][b * 32 + kf + 16];
        s16x8 vf = __builtin_shufflevector(vlo, vhi, 0, 1, 2, 3, 4, 5, 6, 7);
        o[v] = __builtin_amdgcn_mfma_f32_16x16x32_bf16(pf, vf, o[v], 0, 0, 0);
      }
    }
    __builtin_amdgcn_s_setprio(0);
    // write-late: next tile into the other buffer
    if (tt < 15) {
      int nxt = cur ^ 1;
#pragma unroll
      for (int i = 0; i < 3; i++) *(s16x8*)&Kl[nxt][krow[i]][kco[i] * 8] = sk[i];
#pragma unroll
      for (int i = 0; i < 2; i++) *(s16x8*)&Vt[nxt][vd[i]][vco[i] * 8] = sv[i];
      if (v2) *(s16x8*)&Vt[nxt][vd[2]][vco[2] * 8] = sv[2];
    }
  }
  // epilogue: normalize by l (lives at lane 4lq+r), store d<72
#pragma unroll
  for (int r = 0; r < 4; r++) {
    float inv = 1.0f / __shfl(l_r, 4 * lq + r);
    int qrow = qrow0 + 4 * lq + r;
    size_t rowbase = (size_t)(t * 1024 + qrow) * 1152 + h * 72;
#pragma unroll
    for (int v = 0; v < 5; v++) {
      int d = v * 16 + l15;
      if (d < 72) att[rowbase + d] = f2b(o[v][r] * inv);
    }
  }
}

extern "C" void kernel_launch(void* const* d_in, const int* in_sizes, int n_in,
                              void* d_out, int out_size, void* d_ws, size_t ws_size,
                              hipStream_t stream) {
  const float* x   = (const float*)d_in[0];
  const float* Wq  = (const float*)d_in[1];
  const float* bq  = (const float*)d_in[2];
  const float* Wkv = (const float*)d_in[3];
  const float* bkv = (const float*)d_in[4];
  const float* qg  = (const float*)d_in[5];
  const float* kg  = (const float*)d_in[6];
  const float* Wo  = (const float*)d_in[7];
  float* out = (float*)d_out;

  char* w = (char*)d_ws;
  unsigned short* xb   = (unsigned short*)w; w += (size_t)8192 * 1152 * 2;     // 18.9 MB
  unsigned short* WqT  = (unsigned short*)w; w += (size_t)1152 * 1152 * 2;     // contiguous with WkvT -> [3456][1152]
  unsigned short* WkvT = (unsigned short*)w; w += (size_t)2304 * 1152 * 2;
  unsigned short* WoT  = (unsigned short*)w; w += (size_t)1152 * 1152 * 2;
  unsigned short* qn   = (unsigned short*)w; w += (size_t)128 * 1024 * 96 * 2; // 25.2 MB
  unsigned short* kn   = (unsigned short*)w; w += (size_t)128 * 1024 * 96 * 2; // 25.2 MB
  unsigned short* vt   = (unsigned short*)w; w += (size_t)128 * 80 * 1024 * 2; // 21.0 MB
  unsigned short* att  = (unsigned short*)w; w += (size_t)8192 * 1152 * 2;     // 18.9 MB

  cvt_bf16_kernel<<<4608, 256, 0, stream>>>(x, xb, 9437184 / 8);
  transpose_cvt_kernel<<<dim3(36, 36), dim3(32, 8), 0, stream>>>(Wq, WqT, 1152, 1152);
  transpose_cvt_kernel<<<dim3(72, 36), dim3(32, 8), 0, stream>>>(Wkv, WkvT, 1152, 2304);
  transpose_cvt_kernel<<<dim3(36, 36), dim3(32, 8), 0, stream>>>(Wo, WoT, 1152, 1152);

  // fused q,k,v^T GEMM: BT = [WqT ; WkvT] = [3456][1152], grid 27*64=1728
  gemm_bt_kernel<3><<<1728, 256, 0, stream>>>(xb, WqT, bq, bkv, 3456, 27, nullptr, qn, kn, vt);
  rmsnorm2_kernel<<<65536, 256, 0, stream>>>(qn, kn, qg, kg);

  attn_kernel<<<2048, 256, 0, stream>>>(qn, kn, vt, att);

  // out = att @ WoT^T, grid 9*64=576
  gemm_bt_kernel<0><<<576, 256, 0, stream>>>(att, WoT, nullptr, nullptr, 1152, 9, out, nullptr, nullptr, nullptr);
}

// Round 9
// 313.293 us; speedup vs baseline: 1.1031x; 1.0463x over previous
//
#include <hip/hip_runtime.h>

// SpatialAttention (QKNorm, no 1/sqrt(d)): B=1,T=8,S=1024,HID=1152,H=16,D=72
// Pipeline: cvt x->bf16 (sigma k-order) | W^T bf16 (sigma) | fused GEMM->q,k,v^T
//           (32x32x16 MFMA, b128 frags, BK=32 gld16 triple-buf, counted vmcnt) |
//           fused rmsnorm q,k | flash attn (LDS dbuf, swapped QK^T) | GEMM -> f32 out
// sigma = swap bits 2<->3 of k within each 16-k block, applied to BOTH GEMM operands
// (k-sum is permutation-invariant) so 32x32 fragments are contiguous 16B in LDS.

typedef __attribute__((ext_vector_type(4))) short s16x4;
typedef __attribute__((ext_vector_type(8))) short s16x8;
typedef __attribute__((ext_vector_type(4))) float f32x4;
typedef __attribute__((ext_vector_type(16))) float f32x16;

__device__ __forceinline__ unsigned short f2b(float x) {
  unsigned u = __float_as_uint(x);
  u += 0x7FFFu + ((u >> 16) & 1u);
  return (unsigned short)(u >> 16);
}
__device__ __forceinline__ float b2f(unsigned short u) {
  return __uint_as_float(((unsigned)u) << 16);
}
__device__ __forceinline__ void gld16(const void* g, void* l) {
  __builtin_amdgcn_global_load_lds(
      (const __attribute__((address_space(1))) void*)g,
      (__attribute__((address_space(3))) void*)l, 16, 0, 0);
}

// ---------------- x -> bf16, sigma k-order (chunk0 = k{0-3,8-11}, chunk1 = k{4-7,12-15}) ----------------
__global__ __launch_bounds__(256) void cvt_bf16_kernel(const float* __restrict__ in,
                                                       unsigned short* __restrict__ out,
                                                       int n16) {
  int i = blockIdx.x * 256 + threadIdx.x;
  if (i >= n16) return;
  const float4* p = (const float4*)(in + (size_t)i * 16);
  float4 a = p[0], b = p[1], c = p[2], d = p[3];
  s16x8 r0, r1;
  r0[0] = (short)f2b(a.x); r0[1] = (short)f2b(a.y); r0[2] = (short)f2b(a.z); r0[3] = (short)f2b(a.w);
  r0[4] = (short)f2b(c.x); r0[5] = (short)f2b(c.y); r0[6] = (short)f2b(c.z); r0[7] = (short)f2b(c.w);
  r1[0] = (short)f2b(b.x); r1[1] = (short)f2b(b.y); r1[2] = (short)f2b(b.z); r1[3] = (short)f2b(b.w);
  r1[4] = (short)f2b(d.x); r1[5] = (short)f2b(d.y); r1[6] = (short)f2b(d.z); r1[7] = (short)f2b(d.w);
  *(s16x8*)(out + (size_t)i * 16) = r0;
  *(s16x8*)(out + (size_t)i * 16 + 8) = r1;
}

// ---------------- W [K][N] f32 -> WT [N][K] bf16, sigma k-order ----------------
__global__ __launch_bounds__(256) void transpose_cvt_kernel(const float* __restrict__ W,
                                                            unsigned short* __restrict__ WT,
                                                            int K, int N) {
  __shared__ float tile[32][33];
  int n0 = blockIdx.x * 32, k0 = blockIdx.y * 32;
  int tx = threadIdx.x, ty = threadIdx.y;
#pragma unroll
  for (int i = 0; i < 4; i++)
    tile[ty + i * 8][tx] = W[(size_t)(k0 + ty + i * 8) * N + n0 + tx];
  __syncthreads();
  int stx = (tx & 19) | ((tx & 4) << 1) | ((tx & 8) >> 1);  // swap bits 2,3
#pragma unroll
  for (int i = 0; i < 4; i++)
    WT[(size_t)(n0 + ty + i * 8) * K + k0 + stx] = f2b(tile[tx][ty + i * 8]);
}

// ---------------- GEMM: C[M,N] = A[M,K] @ BT[N,K]^T (sigma k-order inputs) ----------------
// 32x32x16 MFMA; per wave 64x64 = 2x2 tiles, acc 4 x f32x16.
// BK=32 (64B rows = 4 x 16B chunks). Chunk swizzle: LDS slot j of row r holds global
// chunk j ^ ((r>>1)&3); fragment = ONE ds_read_b128 at slot (2kk+lh)^((l31>>1)&3)
// -> 8 accesses/bank = conflict-free floor. Triple buffer, vmcnt(4) counted, 1 barrier/step.
// MODE 0: outF f32 row-major (no bias), N=1152.
// MODE 3: fused qkv, N=3456: col<1152 -> qn; <2304 -> kn; else -> vt. bias=[bq;bkv].
template <int MODE>
__global__ __launch_bounds__(256) void gemm_bt_kernel(const unsigned short* __restrict__ A,
                                                      const unsigned short* __restrict__ BT,
                                                      const float* __restrict__ biasq,
                                                      const float* __restrict__ biaskv,
                                                      int N, int gx,
                                                      float* __restrict__ outF,
                                                      unsigned short* __restrict__ qn,
                                                      unsigned short* __restrict__ kn,
                                                      unsigned short* __restrict__ vt) {
  constexpr int K = 1152;
  constexpr int NT = K / 32;  // 36
  __shared__ __align__(16) unsigned short As[3 * 4096];  // 3 bufs x [128 rows][32 k]
  __shared__ __align__(16) unsigned short Bs[3 * 4096];
  int tid = threadIdx.x;
  int lane = tid & 63, wave = tid >> 6;
  int wr = (wave >> 1) * 64, wc = (wave & 1) * 64;
  int l31 = lane & 31, lh = lane >> 5;
  // supertile XCD mapping (bijective: grid = gx*64, gx%3==0)
  int bid = blockIdx.x;
  int xcd = bid & 7;
  int w = bid >> 3;
  int st = w / 24, inner = w - st * 24;
  int ibx = inner % 3, iby = inner / 3;
  int bx = st * 3 + ibx;
  int by = xcd * 8 + iby;
  int brow = by * 128, bcol = bx * 128;
  // staging: chunk c = tid + 256*i: row = c>>2, slot j = c&3, src chunk = j ^ ((row>>1)&3)
  const unsigned short* AsrcP[2];
  const unsigned short* BsrcP[2];
  int dst0[2];
#pragma unroll
  for (int i = 0; i < 2; i++) {
    int c = tid + 256 * i;
    int row = c >> 2, j = c & 3;
    int ch = j ^ ((row >> 1) & 3);
    AsrcP[i] = A + (size_t)(brow + row) * K + ch * 8;
    BsrcP[i] = BT + (size_t)(bcol + row) * K + ch * 8;
    dst0[i] = (wave * 64 + 256 * i) * 8;
  }
#define STAGE(KT, BUF)                                          \
  {                                                             \
    int kb = (KT) * 32;                                         \
    gld16(AsrcP[0] + kb, &As[(BUF) * 4096 + dst0[0]]);          \
    gld16(BsrcP[0] + kb, &Bs[(BUF) * 4096 + dst0[0]]);          \
    gld16(AsrcP[1] + kb, &As[(BUF) * 4096 + dst0[1]]);          \
    gld16(BsrcP[1] + kb, &Bs[(BUF) * 4096 + dst0[1]]);          \
  }
  // fragment-read slots
  int fr = (l31 >> 1) & 3;
  int slotk[2] = {(lh ^ fr) * 8, ((2 + lh) ^ fr) * 8};  // u16 offsets
  // prologue: tiles 0,1 -> bufs 0,1
  STAGE(0, 0);
  STAGE(1, 1);
  f32x16 acc[2][2] = {};
  int cur = 0;
  for (int kt = 0; kt < NT; kt++) {
    if (kt < NT - 1)
      asm volatile("s_waitcnt vmcnt(4)\n\ts_barrier" ::: "memory");
    else
      asm volatile("s_waitcnt vmcnt(0)\n\ts_barrier" ::: "memory");
    if (kt + 2 < NT) {
      int nb = (cur == 0) ? 2 : cur - 1;  // (kt+2)%3
      STAGE(kt + 2, nb);
    }
    int ab = cur * 4096;
#pragma unroll
    for (int kk = 0; kk < 2; kk++) {
      int so = slotk[kk];
      s16x8 af[2], bf[2];
#pragma unroll
      for (int m = 0; m < 2; m++)
        af[m] = *(const s16x8*)&As[ab + (wr + m * 32 + l31) * 32 + so];
#pragma unroll
      for (int n = 0; n < 2; n++)
        bf[n] = *(const s16x8*)&Bs[ab + (wc + n * 32 + l31) * 32 + so];
      __builtin_amdgcn_s_setprio(1);
#pragma unroll
      for (int m = 0; m < 2; m++)
#pragma unroll
        for (int n = 0; n < 2; n++)
          acc[m][n] = __builtin_amdgcn_mfma_f32_32x32x16_bf16(af[m], bf[n], acc[m][n], 0, 0, 0);
      __builtin_amdgcn_s_setprio(0);
    }
    cur = (cur == 2) ? 0 : cur + 1;
  }
#undef STAGE
  // epilogue: C/D 32x32 layout: col = l31, row = (reg&3) + 8*(reg>>2) + 4*lh
#pragma unroll
  for (int m = 0; m < 2; m++) {
#pragma unroll
    for (int n = 0; n < 2; n++) {
#pragma unroll
      for (int reg = 0; reg < 16; reg++) {
        int grow = brow + wr + m * 32 + (reg & 3) + 8 * (reg >> 2) + 4 * lh;
        int gcol = bcol + wc + n * 32 + l31;
        float v = acc[m][n][reg];
        if (MODE == 0) {
          outF[(size_t)grow * N + gcol] = v;
        } else {
          v += (gcol < 1152) ? biasq[gcol] : biaskv[gcol - 1152];
          int t = grow >> 10, s = grow & 1023;
          if (gcol < 2304) {
            int c = (gcol < 1152) ? gcol : gcol - 1152;
            int h = c / 72, d = c - h * 72;
            unsigned short* dst = (gcol < 1152) ? qn : kn;
            dst[((size_t)((t * 16 + h) * 1024 + s)) * 96 + d] = f2b(v);
          } else {
            int c = gcol - 2304;
            int h = c / 72, d = c - h * 72;
            vt[((size_t)((t * 16 + h) * 80 + d)) * 1024 + s] = f2b(v);
          }
        }
      }
    }
  }
}

// ---------------- fused per-(row,head) RMSNorm for q and k, zero-fills pads ----------------
__global__ __launch_bounds__(256) void rmsnorm2_kernel(unsigned short* __restrict__ qn,
                                                       unsigned short* __restrict__ kn,
                                                       const float* __restrict__ qg,
                                                       const float* __restrict__ kg) {
  int r = blockIdx.x * 4 + (threadIdx.x >> 6);  // 0..262143
  int isK = r >= 131072;
  int g = isK ? r - 131072 : r;                 // g = th*1024 + s
  unsigned short* buf = isK ? kn : qn;
  const float* gamma = isK ? kg : qg;
  int h = (g >> 10) & 15;
  size_t base = (size_t)g * 96;
  int l = threadIdx.x & 63;
  float e0 = b2f(buf[base + l]);
  float e1 = 0.f;
  if (l < 8) e1 = b2f(buf[base + 64 + l]);
  float ss = e0 * e0 + e1 * e1;
#pragma unroll
  for (int m = 1; m < 64; m <<= 1) ss += __shfl_xor(ss, m);
  float sc = rsqrtf(ss * (1.0f / 72.0f) + 1e-6f);
  buf[base + l] = f2b(e0 * sc * gamma[h * 72 + l]);
  if (l < 32) {
    float v = 0.f;
    if (l < 8) v = e1 * sc * gamma[h * 72 + 64 + l];
    buf[base + 64 + l] = f2b(v);
  }
}

// ---------------- flash attention: LDS dbuf 2-phase, swapped QK^T, P in registers ----------------
// Qn,Kn: [th][1024][96] bf16 (pads zeroed). VtG: [th][80][1024] bf16 (rows 72..79 garbage,
// pollutes only unstored d>=72 outputs). att: [8192][1152] bf16, columns in sigma k-order.
__global__ __launch_bounds__(256) void attn_kernel(const unsigned short* __restrict__ Qn,
                                                   const unsigned short* __restrict__ Kn,
                                                   const unsigned short* __restrict__ VtG,
                                                   unsigned short* __restrict__ att) {
  __shared__ unsigned short Kl[2][64][100];  // pad 100: conflict-light fragment reads
  __shared__ unsigned short Vt[2][80][76];   // pad 76
  int tid = threadIdx.x;
  int lane = tid & 63, wave = tid >> 6;
  int l15 = lane & 15, lq = lane >> 4, kf = lq * 4;
  // bijective XCD swizzle: nwg=2048
  int bid = blockIdx.x;
  int orig = (bid & 7) * 256 + (bid >> 3);
  int qb = orig & 15, th = orig >> 4;
  int t = th >> 4, h = th & 15;
  const unsigned short* Q = Qn + (size_t)th * 1024 * 96;
  const unsigned short* Kp = Kn + (size_t)th * 1024 * 96;
  const unsigned short* Vg = VtG + (size_t)th * 80 * 1024;
  int qrow0 = qb * 64 + wave * 16;
  // staging chunk geometry (per thread: 3 K chunks + up to 3 V chunks)
  int krow[3], kco[3], vd[3], vco[3];
#pragma unroll
  for (int i = 0; i < 3; i++) {
    int c = tid + i * 256;           // 0..767: K chunks (64 rows x 12 chunks)
    krow[i] = c / 12;
    kco[i] = c - 12 * krow[i];
    int cc = tid + i * 256;          // 0..639: V chunks (80 rows x 8 chunks)
    vd[i] = cc >> 3;
    vco[i] = cc & 7;
  }
  bool v2 = tid < 128;               // third V chunk valid only for cc<640
  s16x8 sk[3], sv[3];
  // Q fragments (B-operand: col=l15=q, k=d)
  s16x8 qf[3];
#pragma unroll
  for (int c = 0; c < 3; c++) {
    const unsigned short* p = Q + (size_t)(qrow0 + l15) * 96 + c * 32 + kf;
    s16x4 lo = *(const s16x4*)p;
    s16x4 hi = *(const s16x4*)(p + 16);
    qf[c] = __builtin_shufflevector(lo, hi, 0, 1, 2, 3, 4, 5, 6, 7);
  }
  f32x4 o[5] = {};                   // O[q=4lq+r][d=l15+16v]
  float m_r = -3.0e38f, l_r = 0.f;   // per-lane state for q = l15

  // prologue: stage tile 0 into buf 0
#pragma unroll
  for (int i = 0; i < 3; i++)
    sk[i] = *(const s16x8*)(Kp + (size_t)krow[i] * 96 + kco[i] * 8);
#pragma unroll
  for (int i = 0; i < 2; i++)
    sv[i] = *(const s16x8*)(Vg + (size_t)vd[i] * 1024 + vco[i] * 8);
  if (v2) sv[2] = *(const s16x8*)(Vg + (size_t)vd[2] * 1024 + vco[2] * 8);
#pragma unroll
  for (int i = 0; i < 3; i++) *(s16x8*)&Kl[0][krow[i]][kco[i] * 8] = sk[i];
#pragma unroll
  for (int i = 0; i < 2; i++) *(s16x8*)&Vt[0][vd[i]][vco[i] * 8] = sv[i];
  if (v2) *(s16x8*)&Vt[0][vd[2]][vco[2] * 8] = sv[2];

  for (int tt = 0; tt < 16; tt++) {
    __syncthreads();
    int cur = tt & 1;
    if (tt < 15) {
      int kv1 = (tt + 1) * 64;
#pragma unroll
      for (int i = 0; i < 3; i++)
        sk[i] = *(const s16x8*)(Kp + (size_t)(kv1 + krow[i]) * 96 + kco[i] * 8);
#pragma unroll
      for (int i = 0; i < 2; i++)
        sv[i] = *(const s16x8*)(Vg + (size_t)vd[i] * 1024 + kv1 + vco[i] * 8);
      if (v2) sv[2] = *(const s16x8*)(Vg + (size_t)vd[2] * 1024 + kv1 + vco[2] * 8);
    }
    // S^T = mfma(K, Q): st[n][r] = S[q=l15][kv = n*16 + 4*lq + r]
    f32x4 st[4];
    __builtin_amdgcn_s_setprio(1);
#pragma unroll
    for (int n = 0; n < 4; n++) {
      f32x4 a = {};
#pragma unroll
      for (int c = 0; c < 3; c++) {
        s16x4 lo = *(const s16x4*)&Kl[cur][n * 16 + l15][c * 32 + kf];
        s16x4 hi = *(const s16x4*)&Kl[cur][n * 16 + l15][c * 32 + kf + 16];
        s16x8 kfr = __builtin_shufflevector(lo, hi, 0, 1, 2, 3, 4, 5, 6, 7);
        a = __builtin_amdgcn_mfma_f32_16x16x32_bf16(kfr, qf[c], a, 0, 0, 0);
      }
      st[n] = a;
    }
    __builtin_amdgcn_s_setprio(0);
    // online softmax for q = l15 (16 local + lq-group shfl reduce)
    float tmax = st[0][0];
#pragma unroll
    for (int n = 0; n < 4; n++)
#pragma unroll
      for (int r = 0; r < 4; r++) tmax = fmaxf(tmax, st[n][r]);
    tmax = fmaxf(tmax, __shfl_xor(tmax, 16));
    tmax = fmaxf(tmax, __shfl_xor(tmax, 32));
    float mn = fmaxf(m_r, tmax);
    float scale = __expf(m_r - mn);
    m_r = mn;
    float sum = 0.f;
#pragma unroll
    for (int n = 0; n < 4; n++)
#pragma unroll
      for (int r = 0; r < 4; r++) {
        float p = __expf(st[n][r] - mn);
        st[n][r] = p;
        sum += p;
      }
    sum += __shfl_xor(sum, 16);
    sum += __shfl_xor(sum, 32);
    l_r = l_r * scale + sum;
    // rescale O (scale for q=4lq+r lives at lane 4lq+r)
#pragma unroll
    for (int r = 0; r < 4; r++) {
      float scq = __shfl(scale, 4 * lq + r);
#pragma unroll
      for (int v = 0; v < 5; v++) o[v][r] *= scq;
    }
    // P fragments directly from st registers (A-operand: row=l15=q, k=kv)
    __builtin_amdgcn_s_setprio(1);
#pragma unroll
    for (int b = 0; b < 2; b++) {
      s16x8 pf;
#pragma unroll
      for (int j = 0; j < 8; j++) pf[j] = (short)f2b(st[2 * b + (j >> 2)][j & 3]);
#pragma unroll
      for (int v = 0; v < 5; v++) {
        s16x4 vlo = *(const s16x4*)&Vt[cur][v * 16 + l15][b * 32 + kf];
        s16x4 vhi = *(const s16x4*)&Vt[cur][v * 16 + l15][b * 32 + kf + 16];
        s16x8 vf = __builtin_shufflevector(vlo, vhi, 0, 1, 2, 3, 4, 5, 6, 7);
        o[v] = __builtin_amdgcn_mfma_f32_16x16x32_bf16(pf, vf, o[v], 0, 0, 0);
      }
    }
    __builtin_amdgcn_s_setprio(0);
    // write-late: next tile into the other buffer
    if (tt < 15) {
      int nxt = cur ^ 1;
#pragma unroll
      for (int i = 0; i < 3; i++) *(s16x8*)&Kl[nxt][krow[i]][kco[i] * 8] = sk[i];
#pragma unroll
      for (int i = 0; i < 2; i++) *(s16x8*)&Vt[nxt][vd[i]][vco[i] * 8] = sv[i];
      if (v2) *(s16x8*)&Vt[nxt][vd[2]][vco[2] * 8] = sv[2];
    }
  }
  // epilogue: normalize by l, store d<72 at sigma-permuted column (out-GEMM k-order)
#pragma unroll
  for (int r = 0; r < 4; r++) {
    float inv = 1.0f / __shfl(l_r, 4 * lq + r);
    int qrow = qrow0 + 4 * lq + r;
    size_t rowbase = (size_t)(t * 1024 + qrow) * 1152;
#pragma unroll
    for (int v = 0; v < 5; v++) {
      int d = v * 16 + l15;
      if (d < 72) {
        int col = h * 72 + d;
        int scol = (col & ~12) | ((col & 4) << 1) | ((col & 8) >> 1);
        att[rowbase + scol] = f2b(o[v][r] * inv);
      }
    }
  }
}

extern "C" void kernel_launch(void* const* d_in, const int* in_sizes, int n_in,
                              void* d_out, int out_size, void* d_ws, size_t ws_size,
                              hipStream_t stream) {
  const float* x   = (const float*)d_in[0];
  const float* Wq  = (const float*)d_in[1];
  const float* bq  = (const float*)d_in[2];
  const float* Wkv = (const float*)d_in[3];
  const float* bkv = (const float*)d_in[4];
  const float* qg  = (const float*)d_in[5];
  const float* kg  = (const float*)d_in[6];
  const float* Wo  = (const float*)d_in[7];
  float* out = (float*)d_out;

  char* w = (char*)d_ws;
  unsigned short* xb   = (unsigned short*)w; w += (size_t)8192 * 1152 * 2;     // 18.9 MB
  unsigned short* WqT  = (unsigned short*)w; w += (size_t)1152 * 1152 * 2;     // contiguous with WkvT -> [3456][1152]
  unsigned short* WkvT = (unsigned short*)w; w += (size_t)2304 * 1152 * 2;
  unsigned short* WoT  = (unsigned short*)w; w += (size_t)1152 * 1152 * 2;
  unsigned short* qn   = (unsigned short*)w; w += (size_t)128 * 1024 * 96 * 2; // 25.2 MB
  unsigned short* kn   = (unsigned short*)w; w += (size_t)128 * 1024 * 96 * 2; // 25.2 MB
  unsigned short* vt   = (unsigned short*)w; w += (size_t)128 * 80 * 1024 * 2; // 21.0 MB
  unsigned short* att  = (unsigned short*)w; w += (size_t)8192 * 1152 * 2;     // 18.9 MB

  cvt_bf16_kernel<<<2304, 256, 0, stream>>>(x, xb, 9437184 / 16);
  transpose_cvt_kernel<<<dim3(36, 36), dim3(32, 8), 0, stream>>>(Wq, WqT, 1152, 1152);
  transpose_cvt_kernel<<<dim3(72, 36), dim3(32, 8), 0, stream>>>(Wkv, WkvT, 1152, 2304);
  transpose_cvt_kernel<<<dim3(36, 36), dim3(32, 8), 0, stream>>>(Wo, WoT, 1152, 1152);

  // fused q,k,v^T GEMM: BT = [WqT ; WkvT] = [3456][1152], grid 27*64=1728
  gemm_bt_kernel<3><<<1728, 256, 0, stream>>>(xb, WqT, bq, bkv, 3456, 27, nullptr, qn, kn, vt);
  rmsnorm2_kernel<<<65536, 256, 0, stream>>>(qn, kn, qg, kg);

  attn_kernel<<<2048, 256, 0, stream>>>(qn, kn, vt, att);

  // out = att @ WoT^T, grid 9*64=576
  gemm_bt_kernel<0><<<576, 256, 0, stream>>>(att, WoT, nullptr, nullptr, 1152, 9, out, nullptr, nullptr, nullptr);
}

// Round 10
// 308.890 us; speedup vs baseline: 1.1189x; 1.0143x over previous
//
#include <hip/hip_runtime.h>

// SpatialAttention (QKNorm, no 1/sqrt(d)): B=1,T=8,S=1024,HID=1152,H=16,D=72
// Pipeline: cvt x->bf16 (sigma) | W^T bf16 (sigma) | qkv GEMM (256x128 block, 128x64 wave
//           tile, 32x32x16 MFMA, BK=32 gld16 triple-buf, vmcnt(6)) | rmsnorm q,k |
//           flash attn (LDS dbuf, swapped QK^T) | out GEMM (r9 128x128) -> f32
// sigma = swap bits 2<->3 of k within each 16-k block on BOTH operands (k-sum invariant).

typedef __attribute__((ext_vector_type(4))) short s16x4;
typedef __attribute__((ext_vector_type(8))) short s16x8;
typedef __attribute__((ext_vector_type(4))) float f32x4;
typedef __attribute__((ext_vector_type(16))) float f32x16;

__device__ __forceinline__ unsigned short f2b(float x) {
  unsigned u = __float_as_uint(x);
  u += 0x7FFFu + ((u >> 16) & 1u);
  return (unsigned short)(u >> 16);
}
__device__ __forceinline__ float b2f(unsigned short u) {
  return __uint_as_float(((unsigned)u) << 16);
}
__device__ __forceinline__ void gld16(const void* g, void* l) {
  __builtin_amdgcn_global_load_lds(
      (const __attribute__((address_space(1))) void*)g,
      (__attribute__((address_space(3))) void*)l, 16, 0, 0);
}

// ---------------- x -> bf16, sigma k-order ----------------
__global__ __launch_bounds__(256) void cvt_bf16_kernel(const float* __restrict__ in,
                                                       unsigned short* __restrict__ out,
                                                       int n16) {
  int i = blockIdx.x * 256 + threadIdx.x;
  if (i >= n16) return;
  const float4* p = (const float4*)(in + (size_t)i * 16);
  float4 a = p[0], b = p[1], c = p[2], d = p[3];
  s16x8 r0, r1;
  r0[0] = (short)f2b(a.x); r0[1] = (short)f2b(a.y); r0[2] = (short)f2b(a.z); r0[3] = (short)f2b(a.w);
  r0[4] = (short)f2b(c.x); r0[5] = (short)f2b(c.y); r0[6] = (short)f2b(c.z); r0[7] = (short)f2b(c.w);
  r1[0] = (short)f2b(b.x); r1[1] = (short)f2b(b.y); r1[2] = (short)f2b(b.z); r1[3] = (short)f2b(b.w);
  r1[4] = (short)f2b(d.x); r1[5] = (short)f2b(d.y); r1[6] = (short)f2b(d.z); r1[7] = (short)f2b(d.w);
  *(s16x8*)(out + (size_t)i * 16) = r0;
  *(s16x8*)(out + (size_t)i * 16 + 8) = r1;
}

// ---------------- W [K][N] f32 -> WT [N][K] bf16, sigma k-order ----------------
__global__ __launch_bounds__(256) void transpose_cvt_kernel(const float* __restrict__ W,
                                                            unsigned short* __restrict__ WT,
                                                            int K, int N) {
  __shared__ float tile[32][33];
  int n0 = blockIdx.x * 32, k0 = blockIdx.y * 32;
  int tx = threadIdx.x, ty = threadIdx.y;
#pragma unroll
  for (int i = 0; i < 4; i++)
    tile[ty + i * 8][tx] = W[(size_t)(k0 + ty + i * 8) * N + n0 + tx];
  __syncthreads();
  int stx = (tx & 19) | ((tx & 4) << 1) | ((tx & 8) >> 1);  // swap bits 2,3
#pragma unroll
  for (int i = 0; i < 4; i++)
    WT[(size_t)(n0 + ty + i * 8) * K + k0 + stx] = f2b(tile[tx][ty + i * 8]);
}

// ---------------- fused qkv GEMM: [8192,1152] @ [3456,1152]^T ----------------
// Block 256x128, 4 waves (2M x 2N), wave tile 128x64 (acc 4x2 f32x16).
// BK=32, triple-buffered gld16 (6 loads/wave/step), counted vmcnt(6), 1 barrier/step.
// Chunk swizzle: LDS slot j of row r holds global chunk j ^ ((r>>1)&3);
// fragment = one ds_read_b128 at slot (2kk+lh)^((l31>>1)&3).
// Supertile XCD map: 864 blocks = 8 xcd x (9 st x (3 bx x 4 by)).
__global__ __launch_bounds__(256) void gemm_qkv_kernel(const unsigned short* __restrict__ A,
                                                       const unsigned short* __restrict__ BT,
                                                       const float* __restrict__ biasq,
                                                       const float* __restrict__ biaskv,
                                                       unsigned short* __restrict__ qn,
                                                       unsigned short* __restrict__ kn,
                                                       unsigned short* __restrict__ vt) {
  constexpr int K = 1152;
  constexpr int NT = K / 32;  // 36
  __shared__ __align__(16) unsigned short As[3 * 8192];  // 3 bufs x [256 rows][32 k]
  __shared__ __align__(16) unsigned short Bs[3 * 4096];  // 3 bufs x [128 rows][32 k]
  int tid = threadIdx.x;
  int lane = tid & 63, wave = tid >> 6;
  int wr = (wave >> 1) * 128, wc = (wave & 1) * 64;
  int l31 = lane & 31, lh = lane >> 5;
  int bid = blockIdx.x;
  int xcd = bid & 7;
  int w = bid >> 3;                  // 0..107
  int st = w / 12, inner = w - st * 12;
  int ibx = inner % 3, iby = inner / 3;
  int bx = st * 3 + ibx;             // 0..26
  int by = xcd * 4 + iby;            // 0..31
  int brow = by * 256, bcol = bx * 128;
  // staging sources (pre-swizzled global chunk) + linear LDS dests
  const unsigned short* AsrcP[4];
  const unsigned short* BsrcP[2];
  int dstA[4], dstB[2];
#pragma unroll
  for (int i = 0; i < 4; i++) {
    int c = tid + 256 * i;
    int row = c >> 2, j = c & 3;
    AsrcP[i] = A + (size_t)(brow + row) * K + (j ^ ((row >> 1) & 3)) * 8;
    dstA[i] = (wave * 64 + 256 * i) * 8;
  }
#pragma unroll
  for (int i = 0; i < 2; i++) {
    int c = tid + 256 * i;
    int row = c >> 2, j = c & 3;
    BsrcP[i] = BT + (size_t)(bcol + row) * K + (j ^ ((row >> 1) & 3)) * 8;
    dstB[i] = (wave * 64 + 256 * i) * 8;
  }
#define STAGE(KT, BUF)                                           \
  {                                                              \
    int kb = (KT) * 32;                                          \
    gld16(AsrcP[0] + kb, &As[(BUF) * 8192 + dstA[0]]);           \
    gld16(AsrcP[1] + kb, &As[(BUF) * 8192 + dstA[1]]);           \
    gld16(AsrcP[2] + kb, &As[(BUF) * 8192 + dstA[2]]);           \
    gld16(AsrcP[3] + kb, &As[(BUF) * 8192 + dstA[3]]);           \
    gld16(BsrcP[0] + kb, &Bs[(BUF) * 4096 + dstB[0]]);           \
    gld16(BsrcP[1] + kb, &Bs[(BUF) * 4096 + dstB[1]]);           \
  }
  int fr = (l31 >> 1) & 3;
  int slotk[2] = {(lh ^ fr) * 8, ((2 + lh) ^ fr) * 8};
  STAGE(0, 0);
  STAGE(1, 1);
  f32x16 acc[4][2] = {};
  int cur = 0;
  for (int kt = 0; kt < NT; kt++) {
    if (kt < NT - 1)
      asm volatile("s_waitcnt vmcnt(6)\n\ts_barrier" ::: "memory");
    else
      asm volatile("s_waitcnt vmcnt(0)\n\ts_barrier" ::: "memory");
    if (kt + 2 < NT) {
      int nb = (cur == 0) ? 2 : cur - 1;  // (kt+2)%3
      STAGE(kt + 2, nb);
    }
    int ab = cur * 8192, bb = cur * 4096;
#pragma unroll
    for (int kk = 0; kk < 2; kk++) {
      int so = slotk[kk];
      s16x8 af[4], bf[2];
#pragma unroll
      for (int m = 0; m < 4; m++)
        af[m] = *(const s16x8*)&As[ab + (wr + m * 32 + l31) * 32 + so];
#pragma unroll
      for (int n = 0; n < 2; n++)
        bf[n] = *(const s16x8*)&Bs[bb + (wc + n * 32 + l31) * 32 + so];
      __builtin_amdgcn_s_setprio(1);
#pragma unroll
      for (int m = 0; m < 4; m++)
#pragma unroll
        for (int n = 0; n < 2; n++)
          acc[m][n] = __builtin_amdgcn_mfma_f32_32x32x16_bf16(af[m], bf[n], acc[m][n], 0, 0, 0);
      __builtin_amdgcn_s_setprio(0);
    }
    cur = (cur == 2) ? 0 : cur + 1;
  }
#undef STAGE
  // epilogue: C/D 32x32 layout: col = l31, row = (reg&3) + 8*(reg>>2) + 4*lh
#pragma unroll
  for (int m = 0; m < 4; m++) {
#pragma unroll
    for (int n = 0; n < 2; n++) {
#pragma unroll
      for (int reg = 0; reg < 16; reg++) {
        int grow = brow + wr + m * 32 + (reg & 3) + 8 * (reg >> 2) + 4 * lh;
        int gcol = bcol + wc + n * 32 + l31;
        float v = acc[m][n][reg];
        v += (gcol < 1152) ? biasq[gcol] : biaskv[gcol - 1152];
        int t = grow >> 10, s = grow & 1023;
        if (gcol < 2304) {
          int c = (gcol < 1152) ? gcol : gcol - 1152;
          int h = c / 72, d = c - h * 72;
          unsigned short* dst = (gcol < 1152) ? qn : kn;
          dst[((size_t)((t * 16 + h) * 1024 + s)) * 96 + d] = f2b(v);
        } else {
          int c = gcol - 2304;
          int h = c / 72, d = c - h * 72;
          vt[((size_t)((t * 16 + h) * 80 + d)) * 1024 + s] = f2b(v);
        }
      }
    }
  }
}

// ---------------- out GEMM (r9 structure): C[M,N] = A[M,K] @ BT[N,K]^T, f32 out ----------------
__global__ __launch_bounds__(256) void gemm_out_kernel(const unsigned short* __restrict__ A,
                                                       const unsigned short* __restrict__ BT,
                                                       int N, int gx,
                                                       float* __restrict__ outF) {
  constexpr int K = 1152;
  constexpr int NT = K / 32;  // 36
  __shared__ __align__(16) unsigned short As[3 * 4096];
  __shared__ __align__(16) unsigned short Bs[3 * 4096];
  int tid = threadIdx.x;
  int lane = tid & 63, wave = tid >> 6;
  int wr = (wave >> 1) * 64, wc = (wave & 1) * 64;
  int l31 = lane & 31, lh = lane >> 5;
  int bid = blockIdx.x;
  int xcd = bid & 7;
  int w = bid >> 3;
  int st = w / 24, inner = w - st * 24;
  int ibx = inner % 3, iby = inner / 3;
  int bx = st * 3 + ibx;
  int by = xcd * 8 + iby;
  int brow = by * 128, bcol = bx * 128;
  const unsigned short* AsrcP[2];
  const unsigned short* BsrcP[2];
  int dst0[2];
#pragma unroll
  for (int i = 0; i < 2; i++) {
    int c = tid + 256 * i;
    int row = c >> 2, j = c & 3;
    int ch = j ^ ((row >> 1) & 3);
    AsrcP[i] = A + (size_t)(brow + row) * K + ch * 8;
    BsrcP[i] = BT + (size_t)(bcol + row) * K + ch * 8;
    dst0[i] = (wave * 64 + 256 * i) * 8;
  }
#define STAGE(KT, BUF)                                          \
  {                                                             \
    int kb = (KT) * 32;                                         \
    gld16(AsrcP[0] + kb, &As[(BUF) * 4096 + dst0[0]]);          \
    gld16(BsrcP[0] + kb, &Bs[(BUF) * 4096 + dst0[0]]);          \
    gld16(AsrcP[1] + kb, &As[(BUF) * 4096 + dst0[1]]);          \
    gld16(BsrcP[1] + kb, &Bs[(BUF) * 4096 + dst0[1]]);          \
  }
  int fr = (l31 >> 1) & 3;
  int slotk[2] = {(lh ^ fr) * 8, ((2 + lh) ^ fr) * 8};
  STAGE(0, 0);
  STAGE(1, 1);
  f32x16 acc[2][2] = {};
  int cur = 0;
  for (int kt = 0; kt < NT; kt++) {
    if (kt < NT - 1)
      asm volatile("s_waitcnt vmcnt(4)\n\ts_barrier" ::: "memory");
    else
      asm volatile("s_waitcnt vmcnt(0)\n\ts_barrier" ::: "memory");
    if (kt + 2 < NT) {
      int nb = (cur == 0) ? 2 : cur - 1;
      STAGE(kt + 2, nb);
    }
    int ab = cur * 4096;
#pragma unroll
    for (int kk = 0; kk < 2; kk++) {
      int so = slotk[kk];
      s16x8 af[2], bf[2];
#pragma unroll
      for (int m = 0; m < 2; m++)
        af[m] = *(const s16x8*)&As[ab + (wr + m * 32 + l31) * 32 + so];
#pragma unroll
      for (int n = 0; n < 2; n++)
        bf[n] = *(const s16x8*)&Bs[ab + (wc + n * 32 + l31) * 32 + so];
      __builtin_amdgcn_s_setprio(1);
#pragma unroll
      for (int m = 0; m < 2; m++)
#pragma unroll
        for (int n = 0; n < 2; n++)
          acc[m][n] = __builtin_amdgcn_mfma_f32_32x32x16_bf16(af[m], bf[n], acc[m][n], 0, 0, 0);
      __builtin_amdgcn_s_setprio(0);
    }
    cur = (cur == 2) ? 0 : cur + 1;
  }
#undef STAGE
#pragma unroll
  for (int m = 0; m < 2; m++) {
#pragma unroll
    for (int n = 0; n < 2; n++) {
#pragma unroll
      for (int reg = 0; reg < 16; reg++) {
        int grow = brow + wr + m * 32 + (reg & 3) + 8 * (reg >> 2) + 4 * lh;
        int gcol = bcol + wc + n * 32 + l31;
        outF[(size_t)grow * N + gcol] = acc[m][n][reg];
      }
    }
  }
}

// ---------------- fused per-(row,head) RMSNorm for q and k, zero-fills pads ----------------
__global__ __launch_bounds__(256) void rmsnorm2_kernel(unsigned short* __restrict__ qn,
                                                       unsigned short* __restrict__ kn,
                                                       const float* __restrict__ qg,
                                                       const float* __restrict__ kg) {
  int r = blockIdx.x * 4 + (threadIdx.x >> 6);  // 0..262143
  int isK = r >= 131072;
  int g = isK ? r - 131072 : r;                 // g = th*1024 + s
  unsigned short* buf = isK ? kn : qn;
  const float* gamma = isK ? kg : qg;
  int h = (g >> 10) & 15;
  size_t base = (size_t)g * 96;
  int l = threadIdx.x & 63;
  float e0 = b2f(buf[base + l]);
  float e1 = 0.f;
  if (l < 8) e1 = b2f(buf[base + 64 + l]);
  float ss = e0 * e0 + e1 * e1;
#pragma unroll
  for (int m = 1; m < 64; m <<= 1) ss += __shfl_xor(ss, m);
  float sc = rsqrtf(ss * (1.0f / 72.0f) + 1e-6f);
  buf[base + l] = f2b(e0 * sc * gamma[h * 72 + l]);
  if (l < 32) {
    float v = 0.f;
    if (l < 8) v = e1 * sc * gamma[h * 72 + 64 + l];
    buf[base + 64 + l] = f2b(v);
  }
}

// ---------------- flash attention: LDS dbuf 2-phase, swapped QK^T, P in registers ----------------
__global__ __launch_bounds__(256) void attn_kernel(const unsigned short* __restrict__ Qn,
                                                   const unsigned short* __restrict__ Kn,
                                                   const unsigned short* __restrict__ VtG,
                                                   unsigned short* __restrict__ att) {
  __shared__ unsigned short Kl[2][64][100];
  __shared__ unsigned short Vt[2][80][76];
  int tid = threadIdx.x;
  int lane = tid & 63, wave = tid >> 6;
  int l15 = lane & 15, lq = lane >> 4, kf = lq * 4;
  int bid = blockIdx.x;
  int orig = (bid & 7) * 256 + (bid >> 3);
  int qb = orig & 15, th = orig >> 4;
  int t = th >> 4, h = th & 15;
  const unsigned short* Q = Qn + (size_t)th * 1024 * 96;
  const unsigned short* Kp = Kn + (size_t)th * 1024 * 96;
  const unsigned short* Vg = VtG + (size_t)th * 80 * 1024;
  int qrow0 = qb * 64 + wave * 16;
  int krow[3], kco[3], vd[3], vco[3];
#pragma unroll
  for (int i = 0; i < 3; i++) {
    int c = tid + i * 256;
    krow[i] = c / 12;
    kco[i] = c - 12 * krow[i];
    int cc = tid + i * 256;
    vd[i] = cc >> 3;
    vco[i] = cc & 7;
  }
  bool v2 = tid < 128;
  s16x8 sk[3], sv[3];
  s16x8 qf[3];
#pragma unroll
  for (int c = 0; c < 3; c++) {
    const unsigned short* p = Q + (size_t)(qrow0 + l15) * 96 + c * 32 + kf;
    s16x4 lo = *(const s16x4*)p;
    s16x4 hi = *(const s16x4*)(p + 16);
    qf[c] = __builtin_shufflevector(lo, hi, 0, 1, 2, 3, 4, 5, 6, 7);
  }
  f32x4 o[5] = {};
  float m_r = -3.0e38f, l_r = 0.f;

#pragma unroll
  for (int i = 0; i < 3; i++)
    sk[i] = *(const s16x8*)(Kp + (size_t)krow[i] * 96 + kco[i] * 8);
#pragma unroll
  for (int i = 0; i < 2; i++)
    sv[i] = *(const s16x8*)(Vg + (size_t)vd[i] * 1024 + vco[i] * 8);
  if (v2) sv[2] = *(const s16x8*)(Vg + (size_t)vd[2] * 1024 + vco[2] * 8);
#pragma unroll
  for (int i = 0; i < 3; i++) *(s16x8*)&Kl[0][krow[i]][kco[i] * 8] = sk[i];
#pragma unroll
  for (int i = 0; i < 2; i++) *(s16x8*)&Vt[0][vd[i]][vco[i] * 8] = sv[i];
  if (v2) *(s16x8*)&Vt[0][vd[2]][vco[2] * 8] = sv[2];

  for (int tt = 0; tt < 16; tt++) {
    __syncthreads();
    int cur = tt & 1;
    if (tt < 15) {
      int kv1 = (tt + 1) * 64;
#pragma unroll
      for (int i = 0; i < 3; i++)
        sk[i] = *(const s16x8*)(Kp + (size_t)(kv1 + krow[i]) * 96 + kco[i] * 8);
#pragma unroll
      for (int i = 0; i < 2; i++)
        sv[i] = *(const s16x8*)(Vg + (size_t)vd[i] * 1024 + kv1 + vco[i] * 8);
      if (v2) sv[2] = *(const s16x8*)(Vg + (size_t)vd[2] * 1024 + kv1 + vco[2] * 8);
    }
    f32x4 st[4];
    __builtin_amdgcn_s_setprio(1);
#pragma unroll
    for (int n = 0; n < 4; n++) {
      f32x4 a = {};
#pragma unroll
      for (int c = 0; c < 3; c++) {
        s16x4 lo = *(const s16x4*)&Kl[cur][n * 16 + l15][c * 32 + kf];
        s16x4 hi = *(const s16x4*)&Kl[cur][n * 16 + l15][c * 32 + kf + 16];
        s16x8 kfr = __builtin_shufflevector(lo, hi, 0, 1, 2, 3, 4, 5, 6, 7);
        a = __builtin_amdgcn_mfma_f32_16x16x32_bf16(kfr, qf[c], a, 0, 0, 0);
      }
      st[n] = a;
    }
    __builtin_amdgcn_s_setprio(0);
    float tmax = st[0][0];
#pragma unroll
    for (int n = 0; n < 4; n++)
#pragma unroll
      for (int r = 0; r < 4; r++) tmax = fmaxf(tmax, st[n][r]);
    tmax = fmaxf(tmax, __shfl_xor(tmax, 16));
    tmax = fmaxf(tmax, __shfl_xor(tmax, 32));
    float mn = fmaxf(m_r, tmax);
    float scale = __expf(m_r - mn);
    m_r = mn;
    float sum = 0.f;
#pragma unroll
    for (int n = 0; n < 4; n++)
#pragma unroll
      for (int r = 0; r < 4; r++) {
        float p = __expf(st[n][r] - mn);
        st[n][r] = p;
        sum += p;
      }
    sum += __shfl_xor(sum, 16);
    sum += __shfl_xor(sum, 32);
    l_r = l_r * scale + sum;
#pragma unroll
    for (int r = 0; r < 4; r++) {
      float scq = __shfl(scale, 4 * lq + r);
#pragma unroll
      for (int v = 0; v < 5; v++) o[v][r] *= scq;
    }
    __builtin_amdgcn_s_setprio(1);
#pragma unroll
    for (int b = 0; b < 2; b++) {
      s16x8 pf;
#pragma unroll
      for (int j = 0; j < 8; j++) pf[j] = (short)f2b(st[2 * b + (j >> 2)][j & 3]);
#pragma unroll
      for (int v = 0; v < 5; v++) {
        s16x4 vlo = *(const s16x4*)&Vt[cur][v * 16 + l15][b * 32 + kf];
        s16x4 vhi = *(const s16x4*)&Vt[cur][v * 16 + l15][b * 32 + kf + 16];
        s16x8 vf = __builtin_shufflevector(vlo, vhi, 0, 1, 2, 3, 4, 5, 6, 7);
        o[v] = __builtin_amdgcn_mfma_f32_16x16x32_bf16(pf, vf, o[v], 0, 0, 0);
      }
    }
    __builtin_amdgcn_s_setprio(0);
    if (tt < 15) {
      int nxt = cur ^ 1;
#pragma unroll
      for (int i = 0; i < 3; i++) *(s16x8*)&Kl[nxt][krow[i]][kco[i] * 8] = sk[i];
#pragma unroll
      for (int i = 0; i < 2; i++) *(s16x8*)&Vt[nxt][vd[i]][vco[i] * 8] = sv[i];
      if (v2) *(s16x8*)&Vt[nxt][vd[2]][vco[2] * 8] = sv[2];
    }
  }
#pragma unroll
  for (int r = 0; r < 4; r++) {
    float inv = 1.0f / __shfl(l_r, 4 * lq + r);
    int qrow = qrow0 + 4 * lq + r;
    size_t rowbase = (size_t)(t * 1024 + qrow) * 1152;
#pragma unroll
    for (int v = 0; v < 5; v++) {
      int d = v * 16 + l15;
      if (d < 72) {
        int col = h * 72 + d;
        int scol = (col & ~12) | ((col & 4) << 1) | ((col & 8) >> 1);
        att[rowbase + scol] = f2b(o[v][r] * inv);
      }
    }
  }
}

extern "C" void kernel_launch(void* const* d_in, const int* in_sizes, int n_in,
                              void* d_out, int out_size, void* d_ws, size_t ws_size,
                              hipStream_t stream) {
  const float* x   = (const float*)d_in[0];
  const float* Wq  = (const float*)d_in[1];
  const float* bq  = (const float*)d_in[2];
  const float* Wkv = (const float*)d_in[3];
  const float* bkv = (const float*)d_in[4];
  const float* qg  = (const float*)d_in[5];
  const float* kg  = (const float*)d_in[6];
  const float* Wo  = (const float*)d_in[7];
  float* out = (float*)d_out;

  char* w = (char*)d_ws;
  unsigned short* xb   = (unsigned short*)w; w += (size_t)8192 * 1152 * 2;
  unsigned short* WqT  = (unsigned short*)w; w += (size_t)1152 * 1152 * 2;  // contiguous with WkvT
  unsigned short* WkvT = (unsigned short*)w; w += (size_t)2304 * 1152 * 2;
  unsigned short* WoT  = (unsigned short*)w; w += (size_t)1152 * 1152 * 2;
  unsigned short* qn   = (unsigned short*)w; w += (size_t)128 * 1024 * 96 * 2;
  unsigned short* kn   = (unsigned short*)w; w += (size_t)128 * 1024 * 96 * 2;
  unsigned short* vt   = (unsigned short*)w; w += (size_t)128 * 80 * 1024 * 2;
  unsigned short* att  = (unsigned short*)w; w += (size_t)8192 * 1152 * 2;

  cvt_bf16_kernel<<<2304, 256, 0, stream>>>(x, xb, 9437184 / 16);
  transpose_cvt_kernel<<<dim3(36, 36), dim3(32, 8), 0, stream>>>(Wq, WqT, 1152, 1152);
  transpose_cvt_kernel<<<dim3(72, 36), dim3(32, 8), 0, stream>>>(Wkv, WkvT, 1152, 2304);
  transpose_cvt_kernel<<<dim3(36, 36), dim3(32, 8), 0, stream>>>(Wo, WoT, 1152, 1152);

  // fused q,k,v^T GEMM: BT = [WqT ; WkvT] = [3456][1152], grid 32*27=864
  gemm_qkv_kernel<<<864, 256, 0, stream>>>(xb, WqT, bq, bkv, qn, kn, vt);
  rmsnorm2_kernel<<<65536, 256, 0, stream>>>(qn, kn, qg, kg);

  attn_kernel<<<2048, 256, 0, stream>>>(qn, kn, vt, att);

  // out = att @ WoT^T, grid 9*64=576
  gemm_out_kernel<<<576, 256, 0, stream>>>(att, WoT, 1152, 9, out);
}